// Round 2
// baseline (905.348 us; speedup 1.0000x reference)
//
#include <hip/hip_runtime.h>
#include <math.h>

#define NTHR 256

// Round-to-nearest-even fp32 -> bf16 bits (NaN irrelevant for this workload)
__device__ __forceinline__ unsigned short f2bf(float x) {
    unsigned int u = __float_as_uint(x);
    return (unsigned short)((u + 0x7fffu + ((u >> 16) & 1u)) >> 16);
}
__device__ __forceinline__ ushort4 pack4(float a, float b, float c, float d) {
    return make_ushort4(f2bf(a), f2bf(b), f2bf(c), f2bf(d));
}

// One "SAGE layer": out[m][c] = relu( sum_f mean_k(deep[m*16+k][f]) * W[f][c]
//                                   + sum_f shallow[m][f]           * W[128+f][c] + bias[c] )
// deep: [M*16,128] fp32, shallow: [M,128] fp32, W: [256,128] fp32 row-major, out: [M,128] fp32.
// A-tile staged in LDS as bf16 (harness threshold is bf16-floor): TM x (256+8 pad).
// TM=64: 33 KB LDS -> 4 blocks/CU (16 waves/CU), launch_bounds(256,4) caps VGPR at 128.
template<int TM>
__global__ __launch_bounds__(NTHR, 4)
void layer_kernel(const float* __restrict__ deep,
                  const float* __restrict__ shallow,
                  const float* __restrict__ W,
                  const float* __restrict__ bias,
                  float* __restrict__ out)
{
    constexpr int RP = TM / 16;            // rows per thread in phase 2
    __shared__ unsigned short A[TM][264];  // 256 cols + 8 bf16 pad (breaks 4-way banking)
    const int t  = threadIdx.x;
    const int m0 = blockIdx.x * TM;

    // ---- Phase 1: mean-reduce 16 deep rows + shallow row -> bf16 LDS tile ----
    {
        const int r8 = t >> 5;          // 0..7 row group
        const int l  = t & 31;          // lane covers 4 consecutive floats
        const int fo = l * 4;
        for (int rr = r8; rr < TM; rr += 8) {
            const int m = m0 + rr;
            const float4* dp = (const float4*)(deep + (size_t)m * 2048 + fo);
            float4 s = dp[0];
            #pragma unroll
            for (int k = 1; k < 16; ++k) {
                float4 v = dp[k * 32];   // deep row stride = 128 floats = 32 float4
                s.x += v.x; s.y += v.y; s.z += v.z; s.w += v.w;
            }
            const float inv = 1.0f / 16.0f;
            float4 sh = *(const float4*)(shallow + (size_t)m * 128 + fo);
            *(ushort4*)&A[rr][fo]       = pack4(s.x * inv, s.y * inv, s.z * inv, s.w * inv);
            *(ushort4*)&A[rr][128 + fo] = pack4(sh.x, sh.y, sh.z, sh.w);
        }
    }
    __syncthreads();

    // ---- Phase 2: TMx128 GEMM tile; thread = RP rows x 8 cols; fp32 accumulate ----
    const int ty = t >> 4;   // 0..15
    const int tx = t & 15;   // 0..15
    float acc[RP][8];
    #pragma unroll
    for (int i = 0; i < RP; ++i)
        #pragma unroll
        for (int j = 0; j < 8; ++j) acc[i][j] = 0.0f;

    const float* Wp = W + tx * 8;
    for (int kk = 0; kk < 256; kk += 4) {
        float av[RP][4];
        #pragma unroll
        for (int i = 0; i < RP; ++i) {
            const int r = ty * RP + i;
            uint2 q = *(const uint2*)&A[r][kk];          // 4 bf16, 16-lane broadcast
            av[i][0] = __uint_as_float(q.x << 16);
            av[i][1] = __uint_as_float(q.x & 0xffff0000u);
            av[i][2] = __uint_as_float(q.y << 16);
            av[i][3] = __uint_as_float(q.y & 0xffff0000u);
        }
        float4 w0[4], w1[4];
        #pragma unroll
        for (int d = 0; d < 4; ++d) {
            const float* wr = Wp + (kk + d) * 128;
            w0[d] = *(const float4*)(wr);
            w1[d] = *(const float4*)(wr + 4);
        }
        #pragma unroll
        for (int i = 0; i < RP; ++i) {
            const float a0 = av[i][0], a1 = av[i][1], a2 = av[i][2], a3 = av[i][3];
            acc[i][0] += a0*w0[0].x + a1*w0[1].x + a2*w0[2].x + a3*w0[3].x;
            acc[i][1] += a0*w0[0].y + a1*w0[1].y + a2*w0[2].y + a3*w0[3].y;
            acc[i][2] += a0*w0[0].z + a1*w0[1].z + a2*w0[2].z + a3*w0[3].z;
            acc[i][3] += a0*w0[0].w + a1*w0[1].w + a2*w0[2].w + a3*w0[3].w;
            acc[i][4] += a0*w1[0].x + a1*w1[1].x + a2*w1[2].x + a3*w1[3].x;
            acc[i][5] += a0*w1[0].y + a1*w1[1].y + a2*w1[2].y + a3*w1[3].y;
            acc[i][6] += a0*w1[0].z + a1*w1[1].z + a2*w1[2].z + a3*w1[3].z;
            acc[i][7] += a0*w1[0].w + a1*w1[1].w + a2*w1[2].w + a3*w1[3].w;
        }
    }

    // ---- Epilogue: +bias, relu, fp32 store ----
    const float4 b0 = *(const float4*)(bias + tx * 8);
    const float4 b1 = *(const float4*)(bias + tx * 8 + 4);
    #pragma unroll
    for (int i = 0; i < RP; ++i) {
        const int m = m0 + ty * RP + i;
        float4 o0 = make_float4(fmaxf(acc[i][0] + b0.x, 0.0f),
                                fmaxf(acc[i][1] + b0.y, 0.0f),
                                fmaxf(acc[i][2] + b0.z, 0.0f),
                                fmaxf(acc[i][3] + b0.w, 0.0f));
        float4 o1 = make_float4(fmaxf(acc[i][4] + b1.x, 0.0f),
                                fmaxf(acc[i][5] + b1.y, 0.0f),
                                fmaxf(acc[i][6] + b1.z, 0.0f),
                                fmaxf(acc[i][7] + b1.w, 0.0f));
        float* op = out + (size_t)m * 128 + tx * 8;
        *(float4*)op       = o0;
        *(float4*)(op + 4) = o1;
    }
}

// Head: z = h0 @ lin1_W + lin1_b; BatchNorm (biased batch stats); sigmoid(zn @ lin2_W + lin2_b)
__global__ __launch_bounds__(NTHR)
void head_kernel(const float* __restrict__ h0,     // [256][128]
                 const float* __restrict__ l1W,    // [128][8]
                 const float* __restrict__ l1b,    // [8]
                 const float* __restrict__ gamma,  // [8]
                 const float* __restrict__ beta,   // [8]
                 const float* __restrict__ l2W,    // [8][2]
                 const float* __restrict__ l2b,    // [2]
                 float* __restrict__ out)          // [256][2]
{
    __shared__ float z[256][8];
    __shared__ float w1s[128 * 8];
    __shared__ float ps[32][8];
    __shared__ float pq[32][8];
    __shared__ float scale_s[8], shift_s[8];

    const int t  = threadIdx.x;
    const int j  = t & 7;
    const int rg = t >> 3;   // 0..31

    #pragma unroll
    for (int i = 0; i < 4; ++i) w1s[t * 4 + i] = l1W[t * 4 + i];
    __syncthreads();

    const float bj = l1b[j];
    for (int it = 0; it < 8; ++it) {
        const int b = it * 32 + rg;
        const float4* hr = (const float4*)(h0 + (size_t)b * 128);
        float s = bj;
        #pragma unroll
        for (int f4 = 0; f4 < 32; ++f4) {
            float4 h = hr[f4];
            s += h.x * w1s[(f4 * 4 + 0) * 8 + j];
            s += h.y * w1s[(f4 * 4 + 1) * 8 + j];
            s += h.z * w1s[(f4 * 4 + 2) * 8 + j];
            s += h.w * w1s[(f4 * 4 + 3) * 8 + j];
        }
        z[b][j] = s;
    }
    __syncthreads();

    {
        float s = 0.0f, q = 0.0f;
        #pragma unroll
        for (int r = 0; r < 8; ++r) {
            float v = z[rg * 8 + r][j];
            s += v; q += v * v;
        }
        ps[rg][j] = s; pq[rg][j] = q;
    }
    __syncthreads();

    if (t < 8) {
        float s = 0.0f, q = 0.0f;
        #pragma unroll
        for (int p = 0; p < 32; ++p) { s += ps[p][t]; q += pq[p][t]; }
        const float mu  = s * (1.0f / 256.0f);
        const float var = q * (1.0f / 256.0f) - mu * mu;
        const float sc  = gamma[t] * rsqrtf(var + 1e-5f);
        scale_s[t] = sc;
        shift_s[t] = beta[t] - mu * sc;
    }
    __syncthreads();

    {
        float o0 = l2b[0], o1 = l2b[1];
        #pragma unroll
        for (int jj = 0; jj < 8; ++jj) {
            const float zn = z[t][jj] * scale_s[jj] + shift_s[jj];
            o0 += zn * l2W[jj * 2 + 0];
            o1 += zn * l2W[jj * 2 + 1];
        }
        out[t * 2 + 0] = 1.0f / (1.0f + expf(-o0));
        out[t * 2 + 1] = 1.0f / (1.0f + expf(-o1));
    }
}

extern "C" void kernel_launch(void* const* d_in, const int* in_sizes, int n_in,
                              void* d_out, int out_size, void* d_ws, size_t ws_size,
                              hipStream_t stream)
{
    const float* x0    = (const float*)d_in[0];
    const float* x1    = (const float*)d_in[1];
    const float* x2    = (const float*)d_in[2];
    const float* x3    = (const float*)d_in[3];
    const float* W0    = (const float*)d_in[4];
    const float* b0    = (const float*)d_in[5];
    const float* W1    = (const float*)d_in[6];
    const float* b1    = (const float*)d_in[7];
    const float* W2    = (const float*)d_in[8];
    const float* b2    = (const float*)d_in[9];
    const float* l1W   = (const float*)d_in[10];
    const float* l1b   = (const float*)d_in[11];
    const float* gamma = (const float*)d_in[12];
    const float* beta  = (const float*)d_in[13];
    const float* l2W   = (const float*)d_in[14];
    const float* l2b   = (const float*)d_in[15];
    float* out = (float*)d_out;

    float* h2 = (float*)d_ws;                        // 65536*128 fp32 = 33.6 MB
    float* h1 = h2 + (size_t)65536 * 128;            // 4096*128 fp32
    float* h0 = h1 + (size_t)4096 * 128;             // 256*128 fp32

    // Layer 3: M = 65536 out-rows, TM=64 -> 1024 blocks
    hipLaunchKernelGGL((layer_kernel<64>), dim3(65536 / 64), dim3(NTHR), 0, stream,
                       x3, x2, W2, b2, h2);
    // Layer 2: M = 4096, TM=32 -> 128 blocks
    hipLaunchKernelGGL((layer_kernel<32>), dim3(4096 / 32), dim3(NTHR), 0, stream,
                       h2, x1, W1, b1, h1);
    // Layer 1: M = 256, TM=16 -> 16 blocks
    hipLaunchKernelGGL((layer_kernel<16>), dim3(256 / 16), dim3(NTHR), 0, stream,
                       h1, x0, W0, b0, h0);
    // Head
    hipLaunchKernelGGL(head_kernel, dim3(1), dim3(NTHR), 0, stream,
                       h0, l1W, l1b, gamma, beta, l2W, l2b, out);
}

// Round 3
// 761.849 us; speedup vs baseline: 1.1884x; 1.1884x over previous
//
#include <hip/hip_runtime.h>
#include <math.h>

#define NTHR 256

typedef __bf16 bf16x8 __attribute__((ext_vector_type(8)));
typedef float  f32x4  __attribute__((ext_vector_type(4)));

// Round-to-nearest-even fp32 -> bf16 bits
__device__ __forceinline__ unsigned short f2bf(float x) {
    unsigned int u = __float_as_uint(x);
    return (unsigned short)((u + 0x7fffu + ((u >> 16) & 1u)) >> 16);
}
__device__ __forceinline__ ushort4 pack4(float a, float b, float c, float d) {
    return make_ushort4(f2bf(a), f2bf(b), f2bf(c), f2bf(d));
}

// One "SAGE layer": out[m][c] = relu( [mean_k deep[m*16+k] | shallow[m]] @ W + bias )
// deep: [M*16,128] fp32, shallow: [M,128] fp32, W: [256,128] fp32, out: [M,128] fp32.
// Phase 1: mean-reduce -> bf16 LDS tile [TM][256+8pad] (row-major).
// Phase 2: MFMA 16x16x32 bf16. Wave w owns cols [w*32, w*32+32); its W slice lives
// in 16 B-fragments (64 VGPRs), loaded ONCE per block (128 KB/block total, no
// redundant W traffic). Hot loop = ds_read_b128 + mfma only.
template<int TM>
__global__ __launch_bounds__(NTHR, 3)
void layer_kernel(const float* __restrict__ deep,
                  const float* __restrict__ shallow,
                  const float* __restrict__ W,
                  const float* __restrict__ bias,
                  float* __restrict__ out)
{
    constexpr int MT = TM / 16;            // 16-row m-tiles per block
    __shared__ unsigned short A[TM][264];  // bf16 bits; stride 264 -> 2-way banks (free)
    const int t  = threadIdx.x;
    const int m0 = blockIdx.x * TM;

    // ---- Phase 1: mean-reduce 16 deep rows + shallow -> bf16 LDS tile ----
    {
        const int r8 = t >> 5;          // 0..7 row group
        const int l  = t & 31;          // lane covers 4 consecutive floats
        const int fo = l * 4;
        for (int rr = r8; rr < TM; rr += 8) {
            const int m = m0 + rr;
            const float4* dp = (const float4*)(deep + (size_t)m * 2048 + fo);
            float4 s = dp[0];
            #pragma unroll
            for (int k = 1; k < 16; ++k) {
                float4 v = dp[k * 32];   // deep row stride = 128 floats
                s.x += v.x; s.y += v.y; s.z += v.z; s.w += v.w;
            }
            const float inv = 1.0f / 16.0f;
            float4 sh = *(const float4*)(shallow + (size_t)m * 128 + fo);
            *(ushort4*)&A[rr][fo]       = pack4(s.x * inv, s.y * inv, s.z * inv, s.w * inv);
            *(ushort4*)&A[rr][128 + fo] = pack4(sh.x, sh.y, sh.z, sh.w);
        }
    }

    // ---- B-fragments: wave's 32 W-cols, all 256 k, fp32->bf16, in registers ----
    const int l    = t & 63;
    const int w    = t >> 6;    // wave 0..3
    const int lo16 = l & 15;
    const int q    = l >> 4;    // quad 0..3
    const int c0   = w * 32;

    bf16x8 Bf[16];              // [kt][nt]: B[n = c0+nt*16+lo16][k = kt*32+q*8+j]
    #pragma unroll
    for (int kt = 0; kt < 8; ++kt) {
        #pragma unroll
        for (int nt = 0; nt < 2; ++nt) {
            const float* p = W + (size_t)(kt * 32 + q * 8) * 128 + c0 + nt * 16 + lo16;
            union { unsigned short u[8]; bf16x8 v; } tmp;
            #pragma unroll
            for (int j = 0; j < 8; ++j) tmp.u[j] = f2bf(p[(size_t)j * 128]);
            Bf[kt * 2 + nt] = tmp.v;
        }
    }
    __syncthreads();

    // ---- Phase 2: MFMA K-loop (LDS + matrix pipe only) ----
    f32x4 acc[MT][2];
    #pragma unroll
    for (int mt = 0; mt < MT; ++mt) {
        acc[mt][0] = (f32x4){0.f, 0.f, 0.f, 0.f};
        acc[mt][1] = (f32x4){0.f, 0.f, 0.f, 0.f};
    }

    #pragma unroll
    for (int kt = 0; kt < 8; ++kt) {
        #pragma unroll
        for (int mt = 0; mt < MT; ++mt) {
            // A-frag: A[m = mt*16+lo16][k = kt*32 + q*8 + j], 16B aligned (stride 528B)
            bf16x8 Af = *(const bf16x8*)&A[mt * 16 + lo16][kt * 32 + q * 8];
            acc[mt][0] = __builtin_amdgcn_mfma_f32_16x16x32_bf16(Af, Bf[kt * 2 + 0], acc[mt][0], 0, 0, 0);
            acc[mt][1] = __builtin_amdgcn_mfma_f32_16x16x32_bf16(Af, Bf[kt * 2 + 1], acc[mt][1], 0, 0, 0);
        }
    }

    // ---- Epilogue: C/D layout col=lane&15, row=quad*4+reg ----
    const float bn0 = bias[c0 + lo16];
    const float bn1 = bias[c0 + 16 + lo16];
    #pragma unroll
    for (int mt = 0; mt < MT; ++mt) {
        #pragma unroll
        for (int r = 0; r < 4; ++r) {
            const int row = m0 + mt * 16 + q * 4 + r;
            float* op = out + (size_t)row * 128;
            op[c0 + lo16]      = fmaxf(acc[mt][0][r] + bn0, 0.0f);
            op[c0 + 16 + lo16] = fmaxf(acc[mt][1][r] + bn1, 0.0f);
        }
    }
}

// Head: z = h0 @ lin1_W + lin1_b; BatchNorm (biased batch stats); sigmoid(zn @ lin2_W + lin2_b)
__global__ __launch_bounds__(NTHR)
void head_kernel(const float* __restrict__ h0,     // [256][128]
                 const float* __restrict__ l1W,    // [128][8]
                 const float* __restrict__ l1b,    // [8]
                 const float* __restrict__ gamma,  // [8]
                 const float* __restrict__ beta,   // [8]
                 const float* __restrict__ l2W,    // [8][2]
                 const float* __restrict__ l2b,    // [2]
                 float* __restrict__ out)          // [256][2]
{
    __shared__ float z[256][8];
    __shared__ float w1s[128 * 8];
    __shared__ float ps[32][8];
    __shared__ float pq[32][8];
    __shared__ float scale_s[8], shift_s[8];

    const int t  = threadIdx.x;
    const int j  = t & 7;
    const int rg = t >> 3;   // 0..31

    #pragma unroll
    for (int i = 0; i < 4; ++i) w1s[t * 4 + i] = l1W[t * 4 + i];
    __syncthreads();

    const float bj = l1b[j];
    for (int it = 0; it < 8; ++it) {
        const int b = it * 32 + rg;
        const float4* hr = (const float4*)(h0 + (size_t)b * 128);
        float s = bj;
        #pragma unroll
        for (int f4 = 0; f4 < 32; ++f4) {
            float4 h = hr[f4];
            s += h.x * w1s[(f4 * 4 + 0) * 8 + j];
            s += h.y * w1s[(f4 * 4 + 1) * 8 + j];
            s += h.z * w1s[(f4 * 4 + 2) * 8 + j];
            s += h.w * w1s[(f4 * 4 + 3) * 8 + j];
        }
        z[b][j] = s;
    }
    __syncthreads();

    {
        float s = 0.0f, qq = 0.0f;
        #pragma unroll
        for (int r = 0; r < 8; ++r) {
            float v = z[rg * 8 + r][j];
            s += v; qq += v * v;
        }
        ps[rg][j] = s; pq[rg][j] = qq;
    }
    __syncthreads();

    if (t < 8) {
        float s = 0.0f, qq = 0.0f;
        #pragma unroll
        for (int p = 0; p < 32; ++p) { s += ps[p][t]; qq += pq[p][t]; }
        const float mu  = s * (1.0f / 256.0f);
        const float var = qq * (1.0f / 256.0f) - mu * mu;
        const float sc  = gamma[t] * rsqrtf(var + 1e-5f);
        scale_s[t] = sc;
        shift_s[t] = beta[t] - mu * sc;
    }
    __syncthreads();

    {
        float o0 = l2b[0], o1 = l2b[1];
        #pragma unroll
        for (int jj = 0; jj < 8; ++jj) {
            const float zn = z[t][jj] * scale_s[jj] + shift_s[jj];
            o0 += zn * l2W[jj * 2 + 0];
            o1 += zn * l2W[jj * 2 + 1];
        }
        out[t * 2 + 0] = 1.0f / (1.0f + expf(-o0));
        out[t * 2 + 1] = 1.0f / (1.0f + expf(-o1));
    }
}

extern "C" void kernel_launch(void* const* d_in, const int* in_sizes, int n_in,
                              void* d_out, int out_size, void* d_ws, size_t ws_size,
                              hipStream_t stream)
{
    const float* x0    = (const float*)d_in[0];
    const float* x1    = (const float*)d_in[1];
    const float* x2    = (const float*)d_in[2];
    const float* x3    = (const float*)d_in[3];
    const float* W0    = (const float*)d_in[4];
    const float* b0    = (const float*)d_in[5];
    const float* W1    = (const float*)d_in[6];
    const float* b1    = (const float*)d_in[7];
    const float* W2    = (const float*)d_in[8];
    const float* b2    = (const float*)d_in[9];
    const float* l1W   = (const float*)d_in[10];
    const float* l1b   = (const float*)d_in[11];
    const float* gamma = (const float*)d_in[12];
    const float* beta  = (const float*)d_in[13];
    const float* l2W   = (const float*)d_in[14];
    const float* l2b   = (const float*)d_in[15];
    float* out = (float*)d_out;

    float* h2 = (float*)d_ws;                        // 65536*128 fp32 = 33.6 MB
    float* h1 = h2 + (size_t)65536 * 128;
    float* h0 = h1 + (size_t)4096 * 128;

    // Layer 3: M = 65536, TM=64 -> 1024 blocks
    hipLaunchKernelGGL((layer_kernel<64>), dim3(65536 / 64), dim3(NTHR), 0, stream,
                       x3, x2, W2, b2, h2);
    // Layer 2: M = 4096, TM=16 -> 256 blocks
    hipLaunchKernelGGL((layer_kernel<16>), dim3(4096 / 16), dim3(NTHR), 0, stream,
                       h2, x1, W1, b1, h1);
    // Layer 1: M = 256, TM=16 -> 16 blocks
    hipLaunchKernelGGL((layer_kernel<16>), dim3(256 / 16), dim3(NTHR), 0, stream,
                       h1, x0, W0, b0, h0);
    // Head
    hipLaunchKernelGGL(head_kernel, dim3(1), dim3(NTHR), 0, stream,
                       h0, l1W, l1b, gamma, beta, l2W, l2b, out);
}

// Round 4
// 732.712 us; speedup vs baseline: 1.2356x; 1.0398x over previous
//
#include <hip/hip_runtime.h>
#include <math.h>

#define NTHR 256

typedef __bf16 bf16x8 __attribute__((ext_vector_type(8)));
typedef float  f32x4  __attribute__((ext_vector_type(4)));
typedef float  f32x4v __attribute__((ext_vector_type(4)));

// Round-to-nearest-even fp32 -> bf16 bits
__device__ __forceinline__ unsigned short f2bf(float x) {
    unsigned int u = __float_as_uint(x);
    return (unsigned short)((u + 0x7fffu + ((u >> 16) & 1u)) >> 16);
}
__device__ __forceinline__ ushort4 pack4v(f32x4v v) {
    return make_ushort4(f2bf(v[0]), f2bf(v[1]), f2bf(v[2]), f2bf(v[3]));
}
__device__ __forceinline__ f32x4v ntload4(const float* p) {
    return __builtin_nontemporal_load((const f32x4v*)p);
}

// Generic SAGE layer.
//   AGG_IN : A-row = [mean_k deep[m*16+k] | shal[m]]   (deep stride 2048 floats)
//   !AGG_IN: A-row = [deep[m] | shal[m]]               (deep stride 128 floats)
//   AGG_OUT: write mean16 over the TM relu'd output rows -> outp[M/16][128]
//   !AGG_OUT: write all TM relu'd rows -> outp[M][128]
// W: [256][128] fp32. Phase 2 = MFMA 16x16x32 bf16, W slice register-resident
// (loaded once per block: no redundant W traffic in the hot loop).
template<int TM, bool AGG_IN, bool AGG_OUT>
__global__ __launch_bounds__(NTHR, 4)
void layer_kernel(const float* __restrict__ deep,
                  const float* __restrict__ shal,
                  const float* __restrict__ W,
                  const float* __restrict__ bias,
                  float* __restrict__ outp)
{
    constexpr int MT = TM / 16;
    __shared__ unsigned short A[TM][264];  // bf16 bits; stride 264 -> <=2-way banks (free)
    const int t  = threadIdx.x;
    const int m0 = blockIdx.x * TM;

    // ---- Phase 1: build bf16 A-tile (streaming loads are nontemporal) ----
    {
        const int r8 = t >> 5;
        const int l  = t & 31;
        const int fo = l * 4;
        for (int rr = r8; rr < TM; rr += 8) {
            const int m = m0 + rr;
            f32x4v s, sh;
            if (AGG_IN) {
                const float* dp = deep + (size_t)m * 2048 + fo;
                s = ntload4(dp);
                #pragma unroll
                for (int k = 1; k < 16; ++k) s += ntload4(dp + k * 128);
                s *= (1.0f / 16.0f);
                sh = ntload4(shal + (size_t)m * 128 + fo);
            } else {
                s  = *(const f32x4v*)(deep + (size_t)m * 128 + fo);
                sh = *(const f32x4v*)(shal + (size_t)m * 128 + fo);
            }
            *(ushort4*)&A[rr][fo]       = pack4v(s);
            *(ushort4*)&A[rr][128 + fo] = pack4v(sh);
        }
    }

    // ---- B-fragments: wave's 32 W-cols, all 256 k, in registers (64 VGPRs) ----
    const int l    = t & 63;
    const int w    = t >> 6;
    const int lo16 = l & 15;
    const int q    = l >> 4;
    const int c0   = w * 32;

    bf16x8 Bf[16];
    #pragma unroll
    for (int kt = 0; kt < 8; ++kt) {
        #pragma unroll
        for (int nt = 0; nt < 2; ++nt) {
            const float* p = W + (size_t)(kt * 32 + q * 8) * 128 + c0 + nt * 16 + lo16;
            union { unsigned short u[8]; bf16x8 v; } tmp;
            #pragma unroll
            for (int j = 0; j < 8; ++j) tmp.u[j] = f2bf(p[(size_t)j * 128]);
            Bf[kt * 2 + nt] = tmp.v;
        }
    }
    __syncthreads();

    // ---- Phase 2: MFMA K-loop (LDS + matrix pipe only) ----
    f32x4 acc[MT][2];
    #pragma unroll
    for (int mt = 0; mt < MT; ++mt) {
        acc[mt][0] = (f32x4){0.f, 0.f, 0.f, 0.f};
        acc[mt][1] = (f32x4){0.f, 0.f, 0.f, 0.f};
    }
    #pragma unroll
    for (int kt = 0; kt < 8; ++kt) {
        #pragma unroll
        for (int mt = 0; mt < MT; ++mt) {
            bf16x8 Af = *(const bf16x8*)&A[mt * 16 + lo16][kt * 32 + q * 8];
            acc[mt][0] = __builtin_amdgcn_mfma_f32_16x16x32_bf16(Af, Bf[kt * 2 + 0], acc[mt][0], 0, 0, 0);
            acc[mt][1] = __builtin_amdgcn_mfma_f32_16x16x32_bf16(Af, Bf[kt * 2 + 1], acc[mt][1], 0, 0, 0);
        }
    }

    // ---- Epilogue: +bias, relu; either store rows or reduce to block means ----
    const float bn0 = bias[c0 + lo16];
    const float bn1 = bias[c0 + 16 + lo16];
    if (AGG_OUT) {
        #pragma unroll
        for (int mt = 0; mt < MT; ++mt) {
            float v0 = 0.f, v1 = 0.f;
            #pragma unroll
            for (int r = 0; r < 4; ++r) {
                v0 += fmaxf(acc[mt][0][r] + bn0, 0.0f);
                v1 += fmaxf(acc[mt][1][r] + bn1, 0.0f);
            }
            v0 += __shfl_xor(v0, 16, 64); v0 += __shfl_xor(v0, 32, 64);
            v1 += __shfl_xor(v1, 16, 64); v1 += __shfl_xor(v1, 32, 64);
            const int g = blockIdx.x * MT + mt;
            if (q == 0) outp[(size_t)g * 128 + c0 + lo16]      = v0 * 0.0625f;
            if (q == 1) outp[(size_t)g * 128 + c0 + 16 + lo16] = v1 * 0.0625f;
        }
    } else {
        #pragma unroll
        for (int mt = 0; mt < MT; ++mt) {
            #pragma unroll
            for (int r = 0; r < 4; ++r) {
                const int row = m0 + mt * 16 + q * 4 + r;
                float* op = outp + (size_t)row * 128;
                op[c0 + lo16]      = fmaxf(acc[mt][0][r] + bn0, 0.0f);
                op[c0 + 16 + lo16] = fmaxf(acc[mt][1][r] + bn1, 0.0f);
            }
        }
    }
}

// Head: z = h0 @ lin1_W + lin1_b; BatchNorm (biased batch stats); sigmoid(zn @ lin2_W + lin2_b)
__global__ __launch_bounds__(NTHR)
void head_kernel(const float* __restrict__ h0,     // [256][128]
                 const float* __restrict__ l1W,    // [128][8]
                 const float* __restrict__ l1b,    // [8]
                 const float* __restrict__ gamma,  // [8]
                 const float* __restrict__ beta,   // [8]
                 const float* __restrict__ l2W,    // [8][2]
                 const float* __restrict__ l2b,    // [2]
                 float* __restrict__ out)          // [256][2]
{
    __shared__ float z[256][8];
    __shared__ float w1s[128 * 8];
    __shared__ float ps[32][8];
    __shared__ float pq[32][8];
    __shared__ float scale_s[8], shift_s[8];

    const int t  = threadIdx.x;
    const int j  = t & 7;
    const int rg = t >> 3;

    #pragma unroll
    for (int i = 0; i < 4; ++i) w1s[t * 4 + i] = l1W[t * 4 + i];
    __syncthreads();

    const float bj = l1b[j];
    for (int it = 0; it < 8; ++it) {
        const int b = it * 32 + rg;
        const float4* hr = (const float4*)(h0 + (size_t)b * 128);
        float s = bj;
        #pragma unroll
        for (int f4 = 0; f4 < 32; ++f4) {
            float4 h = hr[f4];
            s += h.x * w1s[(f4 * 4 + 0) * 8 + j];
            s += h.y * w1s[(f4 * 4 + 1) * 8 + j];
            s += h.z * w1s[(f4 * 4 + 2) * 8 + j];
            s += h.w * w1s[(f4 * 4 + 3) * 8 + j];
        }
        z[b][j] = s;
    }
    __syncthreads();

    {
        float s = 0.0f, qq = 0.0f;
        #pragma unroll
        for (int r = 0; r < 8; ++r) {
            float v = z[rg * 8 + r][j];
            s += v; qq += v * v;
        }
        ps[rg][j] = s; pq[rg][j] = qq;
    }
    __syncthreads();

    if (t < 8) {
        float s = 0.0f, qq = 0.0f;
        #pragma unroll
        for (int p = 0; p < 32; ++p) { s += ps[p][t]; qq += pq[p][t]; }
        const float mu  = s * (1.0f / 256.0f);
        const float var = qq * (1.0f / 256.0f) - mu * mu;
        const float sc  = gamma[t] * rsqrtf(var + 1e-5f);
        scale_s[t] = sc;
        shift_s[t] = beta[t] - mu * sc;
    }
    __syncthreads();

    {
        float o0 = l2b[0], o1 = l2b[1];
        #pragma unroll
        for (int jj = 0; jj < 8; ++jj) {
            const float zn = z[t][jj] * scale_s[jj] + shift_s[jj];
            o0 += zn * l2W[jj * 2 + 0];
            o1 += zn * l2W[jj * 2 + 1];
        }
        out[t * 2 + 0] = 1.0f / (1.0f + expf(-o0));
        out[t * 2 + 1] = 1.0f / (1.0f + expf(-o1));
    }
}

extern "C" void kernel_launch(void* const* d_in, const int* in_sizes, int n_in,
                              void* d_out, int out_size, void* d_ws, size_t ws_size,
                              hipStream_t stream)
{
    const float* x0    = (const float*)d_in[0];
    const float* x1    = (const float*)d_in[1];
    const float* x2    = (const float*)d_in[2];
    const float* x3    = (const float*)d_in[3];
    const float* W0    = (const float*)d_in[4];
    const float* b0    = (const float*)d_in[5];
    const float* W1    = (const float*)d_in[6];
    const float* b1    = (const float*)d_in[7];
    const float* W2    = (const float*)d_in[8];
    const float* b2    = (const float*)d_in[9];
    const float* l1W   = (const float*)d_in[10];
    const float* l1b   = (const float*)d_in[11];
    const float* gamma = (const float*)d_in[12];
    const float* beta  = (const float*)d_in[13];
    const float* l2W   = (const float*)d_in[14];
    const float* l2b   = (const float*)d_in[15];
    float* out = (float*)d_out;

    float* h2m = (float*)d_ws;                       // [4096][128] fp32 = 2.1 MB
    float* h1m = h2m + (size_t)4096 * 128;           // [256][128]
    float* h0  = h1m + (size_t)256 * 128;            // [256][128]

    // Layer 3: 65536 fused rows -> mean-reduced h2m [4096][128]; h2 never hits HBM.
    hipLaunchKernelGGL((layer_kernel<64, true, true>), dim3(65536 / 64), dim3(NTHR), 0, stream,
                       x3, x2, W2, b2, h2m);
    // Layer 2: GEMM on [h2m | x1] (4096 rows) -> mean-reduced h1m [256][128].
    hipLaunchKernelGGL((layer_kernel<64, false, true>), dim3(4096 / 64), dim3(NTHR), 0, stream,
                       h2m, x1, W1, b1, h1m);
    // Layer 1: GEMM on [h1m | x0] (256 rows) -> h0 [256][128].
    hipLaunchKernelGGL((layer_kernel<64, false, false>), dim3(256 / 64), dim3(NTHR), 0, stream,
                       h1m, x0, W0, b0, h0);
    // Head
    hipLaunchKernelGGL(head_kernel, dim3(1), dim3(NTHR), 0, stream,
                       h0, l1W, l1b, gamma, beta, l2W, l2b, out);
}